// Round 1
// baseline (409.684 us; speedup 1.0000x reference)
//
#include <hip/hip_runtime.h>

#define N_EDGES_C 1048576
#define LS 136   // LDS row stride in bf16 elements (272B = 17*16B -> bank-spread, 16B aligned)

typedef __attribute__((ext_vector_type(8))) __bf16 bf16x8;
typedef __attribute__((ext_vector_type(4))) float f32x4;
typedef __attribute__((ext_vector_type(4))) unsigned short us4;

#define MFMA16(a,b,c) __builtin_amdgcn_mfma_f32_16x16x32_bf16((a),(b),(c),0,0,0)

__device__ __forceinline__ unsigned short f2bf(float f) {
  unsigned int u = __builtin_bit_cast(unsigned int, f);
  u = (u + 0x7fffu + ((u >> 16) & 1u)) >> 16;
  return (unsigned short)u;
}
__device__ __forceinline__ float bf2f(unsigned short h) {
  unsigned int u = ((unsigned int)h) << 16;
  return __builtin_bit_cast(float, u);
}

// A-operand tile load: stored row-major [M][K], K contiguous, stride LS.
// B-operand tile load: stored [N][K] (i.e. B^T), K contiguous. Same lane map.
__device__ __forceinline__ bf16x8 fragL(const unsigned short* p, int rc, int kb, int lane) {
  return *(const bf16x8*)(p + (rc + (lane & 15)) * LS + kb + ((lane >> 4) << 3));
}
__device__ __forceinline__ bf16x8 fragG(const unsigned short* p, int K, int nc, int kb, int lane) {
  return *(const bf16x8*)(p + (nc + (lane & 15)) * K + kb + ((lane >> 4) << 3));
}

// ---------------- prep: bf16-transpose weights + fold BN into mul/add ----------------
// ws u16 layout: [0)=W0s^T 128x64, [8192)=W0n^T, [16384)=W1s^T 128x128,
//                [32768)=W1n^T, [49152)=Wa^T, end 65536 u16 (131072 B)
// cst f32 (at byte 131072): mul0[128], add0[128], mul1[128], add1[128]
__global__ void prep_kernel(const float* __restrict__ Wc0s, const float* __restrict__ Wc0n,
                            const float* __restrict__ Wc1s, const float* __restrict__ Wc1n,
                            const float* __restrict__ Wa,
                            const float* __restrict__ bc0, const float* __restrict__ g0,
                            const float* __restrict__ b0, const float* __restrict__ m0,
                            const float* __restrict__ v0,
                            const float* __restrict__ bc1, const float* __restrict__ g1,
                            const float* __restrict__ b1, const float* __restrict__ m1,
                            const float* __restrict__ v1,
                            unsigned short* __restrict__ wbf, float* __restrict__ cst) {
  int t = blockIdx.x * blockDim.x + threadIdx.x;
  if (t < 8192) {                       // 64x128 -> [d][f]
    int d = t >> 6, f = t & 63;
    wbf[t]        = f2bf(Wc0s[f * 128 + d]);
    wbf[8192 + t] = f2bf(Wc0n[f * 128 + d]);
  } else if (t < 24576) {               // 128x128 -> [d][k]
    int i = t - 8192;
    int d = i >> 7, k = i & 127;
    wbf[16384 + i] = f2bf(Wc1s[k * 128 + d]);
    wbf[32768 + i] = f2bf(Wc1n[k * 128 + d]);
    wbf[49152 + i] = f2bf(Wa[k * 128 + d]);
  } else if (t < 24704) {
    int d = t - 24576;
    float s0 = g0[d] * rsqrtf(v0[d] + 1e-5f);
    cst[d]       = s0;
    cst[128 + d] = (bc0[d] - m0[d]) * s0 + b0[d];
    float s1 = g1[d] * rsqrtf(v1[d] + 1e-5f);
    cst[256 + d] = s1;
    cst[384 + d] = (bc1[d] - m1[d]) * s1 + b1[d];
  }
}

// ---------------- fused per-graph kernel: 1 block = 1 graph ----------------
__global__ __launch_bounds__(512)
void gnn_fused(const float* __restrict__ x, const float* __restrict__ mwt,
               const int* __restrict__ ei,
               const unsigned short* __restrict__ wbf, const float* __restrict__ cst,
               const float* __restrict__ ba,
               const float* __restrict__ Wr0, const float* __restrict__ br0,
               const float* __restrict__ Wr1, const float* __restrict__ br1,
               const float* __restrict__ Wout, const float* __restrict__ bout,
               float* __restrict__ out) {
  __shared__ unsigned short sAdj[128 * LS];  // Adj[dst][src]; later p[node][d]
  __shared__ unsigned short sH[128 * LS];    // h [node][feat]
  __shared__ unsigned short sHT[128 * LS];   // h^T [feat][node]; later p^T [d][node]
  __shared__ unsigned short sAgg[128 * LS];  // counts scratch; agg[node][feat]; later pair/pairT
  __shared__ float sVec0[128];
  __shared__ float sVec1[128];
  __shared__ float sOut;

  const int g = blockIdx.x;
  const int t = threadIdx.x;
  const int lane = t & 63;
  const int w = t >> 6;              // wave 0..7
  const int col = lane & 15;
  const int r0 = (lane >> 4) << 2;   // D-frag row base within 16x16 tile

  unsigned int* cnt = (unsigned int*)sAgg;   // 8192 words = 128x128 u16 counts
  const f32x4 zero = {0.f, 0.f, 0.f, 0.f};

  // ---- P0a: zero count grid + pooled accumulator
  for (int i = t; i < 8192; i += 512) cnt[i] = 0u;
  if (t < 128) sVec0[t] = 0.f;
  __syncthreads();

  // ---- P0b: edge histogram (512 edges, 1/thread) + load x into sH and sHT
  {
    int e = g * 512 + t;
    int ls_ = ei[e] & 127;
    int ld_ = ei[N_EDGES_C + e] & 127;
    int idx = ld_ * 128 + ls_;
    atomicAdd(&cnt[idx >> 1], 1u << ((idx & 1) * 16));
  }
  {
    const float4* xg = (const float4*)(x + (size_t)g * 8192);
#pragma unroll
    for (int i = 0; i < 4; i++) {
      int vi = t + i * 512;
      float4 v = xg[vi];
      int e0 = vi << 2;
      int node = e0 >> 6;
      int f = e0 & 63;
      unsigned short c0 = f2bf(v.x), c1 = f2bf(v.y), c2 = f2bf(v.z), c3 = f2bf(v.w);
      unsigned short* ph = &sH[node * LS + f];
      ph[0] = c0; ph[1] = c1; ph[2] = c2; ph[3] = c3;
      sHT[(f + 0) * LS + node] = c0;
      sHT[(f + 1) * LS + node] = c1;
      sHT[(f + 2) * LS + node] = c2;
      sHT[(f + 3) * LS + node] = c3;
    }
  }
  __syncthreads();

  // ---- P0c: row-normalized adjacency (bf16), deg clipped at 1
  if (t < 128) {
    int base = t * 64;
    int ssum = 0;
#pragma unroll
    for (int i = 0; i < 64; i++) {
      unsigned int wv = cnt[base + i];
      ssum += (int)(wv & 0xffffu) + (int)(wv >> 16);
    }
    float inv = 1.f / (float)(ssum > 1 ? ssum : 1);
    for (int i = 0; i < 64; i++) {
      unsigned int wv = cnt[base + i];
      sAdj[t * LS + 2 * i]     = f2bf((float)(wv & 0xffffu) * inv);
      sAdj[t * LS + 2 * i + 1] = f2bf((float)(wv >> 16) * inv);
    }
  }
  __syncthreads();

  // ---- P1: agg0 = Adj @ x  -> sAgg[node][f<64]  (counts consumed; safe to overwrite)
  {
    f32x4 acc[4] = {zero, zero, zero, zero};
    for (int kb = 0; kb < 128; kb += 32) {
      bf16x8 a = fragL(sAdj, w * 16, kb, lane);
#pragma unroll
      for (int n = 0; n < 4; n++) {
        bf16x8 b = fragL(sHT, n * 16, kb, lane);
        acc[n] = MFMA16(a, b, acc[n]);
      }
    }
#pragma unroll
    for (int n = 0; n < 4; n++)
#pragma unroll
      for (int r = 0; r < 4; r++)
        sAgg[(w * 16 + r0 + r) * LS + n * 16 + col] = f2bf(acc[n][r]);
  }
  __syncthreads();

  // ---- P2: conv0 = x@W0s + agg0@W0n -> BN0 -> leaky -> sH, sHT  (K=64)
  {
    f32x4 acc[8] = {zero, zero, zero, zero, zero, zero, zero, zero};
    for (int kb = 0; kb < 64; kb += 32) {
      bf16x8 a1 = fragL(sH, w * 16, kb, lane);
      bf16x8 a2 = fragL(sAgg, w * 16, kb, lane);
#pragma unroll
      for (int n = 0; n < 8; n++) {
        bf16x8 b1 = fragG(wbf, 64, n * 16, kb, lane);
        bf16x8 b2 = fragG(wbf + 8192, 64, n * 16, kb, lane);
        acc[n] = MFMA16(a1, b1, acc[n]);
        acc[n] = MFMA16(a2, b2, acc[n]);
      }
    }
    __syncthreads();  // all reads of sH/sAgg done before overwrite
#pragma unroll
    for (int n = 0; n < 8; n++) {
      int d = n * 16 + col;
      float mul = cst[d], add = cst[128 + d];
      unsigned short tb[4];
#pragma unroll
      for (int r = 0; r < 4; r++) {
        float v = acc[n][r] * mul + add;
        v = v > 0.f ? v : 0.01f * v;
        tb[r] = f2bf(v);
        sH[(w * 16 + r0 + r) * LS + d] = tb[r];
      }
      us4 q = {tb[0], tb[1], tb[2], tb[3]};
      *(us4*)&sHT[d * LS + w * 16 + r0] = q;
    }
  }
  __syncthreads();

  // ---- P3: agg1 = Adj @ h1 -> sAgg[node][d]  (K=128)
  {
    f32x4 acc[8] = {zero, zero, zero, zero, zero, zero, zero, zero};
    for (int kb = 0; kb < 128; kb += 32) {
      bf16x8 a = fragL(sAdj, w * 16, kb, lane);
#pragma unroll
      for (int n = 0; n < 8; n++) {
        bf16x8 b = fragL(sHT, n * 16, kb, lane);
        acc[n] = MFMA16(a, b, acc[n]);
      }
    }
#pragma unroll
    for (int n = 0; n < 8; n++)
#pragma unroll
      for (int r = 0; r < 4; r++)
        sAgg[(w * 16 + r0 + r) * LS + n * 16 + col] = f2bf(acc[n][r]);
  }
  __syncthreads();

  // ---- P4: conv1 = h1@W1s + agg1@W1n -> BN1 -> leaky -> *monomer_weight -> sH
  {
    f32x4 acc[8] = {zero, zero, zero, zero, zero, zero, zero, zero};
    for (int kb = 0; kb < 128; kb += 32) {
      bf16x8 a1 = fragL(sH, w * 16, kb, lane);
      bf16x8 a2 = fragL(sAgg, w * 16, kb, lane);
#pragma unroll
      for (int n = 0; n < 8; n++) {
        bf16x8 b1 = fragG(wbf + 16384, 128, n * 16, kb, lane);
        bf16x8 b2 = fragG(wbf + 32768, 128, n * 16, kb, lane);
        acc[n] = MFMA16(a1, b1, acc[n]);
        acc[n] = MFMA16(a2, b2, acc[n]);
      }
    }
    float mwr[4];
#pragma unroll
    for (int r = 0; r < 4; r++) mwr[r] = mwt[(size_t)g * 128 + w * 16 + r0 + r];
    __syncthreads();  // all reads of sH done before overwrite
#pragma unroll
    for (int n = 0; n < 8; n++) {
      int d = n * 16 + col;
      float mul = cst[256 + d], add = cst[384 + d];
#pragma unroll
      for (int r = 0; r < 4; r++) {
        float v = acc[n][r] * mul + add;
        v = v > 0.f ? v : 0.01f * v;
        v *= mwr[r];
        sH[(w * 16 + r0 + r) * LS + d] = f2bf(v);
      }
    }
  }
  __syncthreads();

  // ---- P5: p = leaky(h2 @ Wa + ba) -> p[node][d] in sAdj region, p^T[d][node] in sHT
  {
    f32x4 acc[8] = {zero, zero, zero, zero, zero, zero, zero, zero};
    for (int kb = 0; kb < 128; kb += 32) {
      bf16x8 a = fragL(sH, w * 16, kb, lane);
#pragma unroll
      for (int n = 0; n < 8; n++) {
        bf16x8 b = fragG(wbf + 49152, 128, n * 16, kb, lane);
        acc[n] = MFMA16(a, b, acc[n]);
      }
    }
    // Adj and h1^T are dead; no one reads sAdj/sHT during P5 -> write immediately
#pragma unroll
    for (int n = 0; n < 8; n++) {
      int d = n * 16 + col;
      float bav = ba[d];
      unsigned short tb[4];
#pragma unroll
      for (int r = 0; r < 4; r++) {
        float v = acc[n][r] + bav;
        v = v > 0.f ? v : 0.01f * v;
        tb[r] = f2bf(v);
        sAdj[(w * 16 + r0 + r) * LS + d] = tb[r];
      }
      us4 q = {tb[0], tb[1], tb[2], tb[3]};
      *(us4*)&sHT[d * LS + w * 16 + r0] = q;
    }
  }
  __syncthreads();

  // ---- P6: pair = sigmoid(pA @ pB^T), 64x64; store pair[m][n] and pairT[n][m] in sAgg
  {
    f32x4 acc[2] = {zero, zero};
    for (int kb = 0; kb < 128; kb += 32) {
#pragma unroll
      for (int i = 0; i < 2; i++) {
        int T = w * 2 + i;
        bf16x8 a = fragL(sAdj, (T >> 2) * 16, kb, lane);       // pA rows
        bf16x8 b = fragL(sAdj, 64 + (T & 3) * 16, kb, lane);   // pB rows as B^T
        acc[i] = MFMA16(a, b, acc[i]);
      }
    }
#pragma unroll
    for (int i = 0; i < 2; i++) {
      int T = w * 2 + i;
      int mb = (T >> 2) * 16, nb = (T & 3) * 16;
#pragma unroll
      for (int r = 0; r < 4; r++) {
        float v = 1.f / (1.f + __expf(-acc[i][r]));
        unsigned short u = f2bf(v);
        sAgg[(mb + r0 + r) * LS + nb + col] = u;          // pair[m][n]
        sAgg[(64 + nb + col) * LS + mb + r0 + r] = u;     // pairT[n][m]
      }
    }
  }
  __syncthreads();

  // ---- P7: newA = pair@pB + mA (waves 0-3), newB = pairT@pA + mB (waves 4-7); pooled sum
  {
    const int isB = w >> 2;
    const int mr = (w & 3) * 16;
    f32x4 acc[8] = {zero, zero, zero, zero, zero, zero, zero, zero};
    for (int kb = 0; kb < 64; kb += 32) {
      bf16x8 a = fragL(sAgg, (isB ? 64 + mr : mr), kb, lane);
#pragma unroll
      for (int n = 0; n < 8; n++) {
        bf16x8 b = isB ? fragL(sHT, n * 16, kb, lane)        // p^T[d][m], m in 0..63
                       : fragL(sHT + 64, n * 16, kb, lane);  // p^T[d][64+n]
        acc[n] = MFMA16(a, b, acc[n]);
      }
    }
    int rowbase = isB * 64 + mr;
#pragma unroll
    for (int n = 0; n < 8; n++) {
      int d = n * 16 + col;
      float csum = 0.f;
#pragma unroll
      for (int r = 0; r < 4; r++) {
        float v = acc[n][r] + bf2f(sH[(rowbase + r0 + r) * LS + d]);  // + residual
        csum += v;
      }
      csum += __shfl_xor(csum, 16);
      csum += __shfl_xor(csum, 32);
      if (lane < 16) atomicAdd(&sVec0[d], csum);
    }
  }
  __syncthreads();

  // ---- P8: readout  r = leaky(leaky(pooled@Wr0+br0)@Wr1+br1) @ Wout + bout
  if (t < 128) sVec0[t] *= (1.f / 128.f);
  __syncthreads();
  {
    int d = t >> 2, q = t & 3;
    float s = 0.f;
    for (int j = q * 32; j < q * 32 + 32; j++) s += sVec0[j] * Wr0[j * 128 + d];
    s += __shfl_xor(s, 1);
    s += __shfl_xor(s, 2);
    if (q == 0) { s += br0[d]; sVec1[d] = s > 0.f ? s : 0.01f * s; }
  }
  __syncthreads();
  {
    int d = t >> 2, q = t & 3;
    float s = 0.f;
    for (int j = q * 32; j < q * 32 + 32; j++) s += sVec1[j] * Wr1[j * 128 + d];
    s += __shfl_xor(s, 1);
    s += __shfl_xor(s, 2);
    if (q == 0) { s += br1[d]; sVec0[d] = s > 0.f ? s : 0.01f * s; }
  }
  __syncthreads();
  if (t == 0) sOut = 0.f;
  __syncthreads();
  if (t < 128) atomicAdd(&sOut, sVec0[t] * Wout[t]);
  __syncthreads();
  if (t == 0) out[g] = sOut + bout[0];
}

extern "C" void kernel_launch(void* const* d_in, const int* in_sizes, int n_in,
                              void* d_out, int out_size, void* d_ws, size_t ws_size,
                              hipStream_t stream) {
  const float* x     = (const float*)d_in[0];
  const float* mwt   = (const float*)d_in[1];
  const float* Wc0s  = (const float*)d_in[2];
  const float* Wc0n  = (const float*)d_in[3];
  const float* bc0   = (const float*)d_in[4];
  const float* g0    = (const float*)d_in[5];
  const float* b0    = (const float*)d_in[6];
  const float* m0    = (const float*)d_in[7];
  const float* v0    = (const float*)d_in[8];
  const float* Wc1s  = (const float*)d_in[9];
  const float* Wc1n  = (const float*)d_in[10];
  const float* bc1   = (const float*)d_in[11];
  const float* g1    = (const float*)d_in[12];
  const float* b1    = (const float*)d_in[13];
  const float* m1    = (const float*)d_in[14];
  const float* v1    = (const float*)d_in[15];
  const float* Wa    = (const float*)d_in[16];
  const float* ba    = (const float*)d_in[17];
  const float* Wr0   = (const float*)d_in[18];
  const float* br0   = (const float*)d_in[19];
  const float* Wr1   = (const float*)d_in[20];
  const float* br1   = (const float*)d_in[21];
  const float* Wout  = (const float*)d_in[22];
  const float* bout  = (const float*)d_in[23];
  const int*   ei    = (const int*)d_in[24];

  unsigned short* wbf = (unsigned short*)d_ws;
  float* cst = (float*)((char*)d_ws + 131072);

  prep_kernel<<<dim3(97), dim3(256), 0, stream>>>(Wc0s, Wc0n, Wc1s, Wc1n, Wa,
                                                  bc0, g0, b0, m0, v0,
                                                  bc1, g1, b1, m1, v1, wbf, cst);
  gnn_fused<<<dim3(2048), dim3(512), 0, stream>>>(x, mwt, ei, wbf, cst, ba,
                                                  Wr0, br0, Wr1, br1, Wout, bout,
                                                  (float*)d_out);
}

// Round 2
// 305.062 us; speedup vs baseline: 1.3430x; 1.3430x over previous
//
#include <hip/hip_runtime.h>

#define N_EDGES_C 1048576

typedef __attribute__((ext_vector_type(8))) __bf16 bf16x8;
typedef __attribute__((ext_vector_type(4))) float f32x4;
typedef __attribute__((ext_vector_type(4))) unsigned short us4;

#define MFMA16(a,b,c) __builtin_amdgcn_mfma_f32_16x16x32_bf16((a),(b),(c),0,0,0)

__device__ __forceinline__ unsigned short f2bf(float f) {
  unsigned int u = __builtin_bit_cast(unsigned int, f);
  u = (u + 0x7fffu + ((u >> 16) & 1u)) >> 16;
  return (unsigned short)u;
}

// global weights, [N][K] layout (B^T), K contiguous, no padding
__device__ __forceinline__ bf16x8 fragG(const unsigned short* p, int K, int nc, int kb, int lane) {
  return *(const bf16x8*)(p + (nc + (lane & 15)) * K + kb + ((lane >> 4) << 3));
}
// swizzled 128x128 bf16 LDS tile (row stride 256B, byte ^= (row&7)<<4)
__device__ __forceinline__ bf16x8 fragM(const unsigned short* sM, int row, int kb, int lane) {
  int r = row + (lane & 15);
  int cb = (kb + ((lane >> 4) << 3)) * 2;
  return *(const bf16x8*)((const char*)sM + r * 256 + (cb ^ ((r & 7) << 4)));
}
__device__ __forceinline__ void putU16(unsigned short* sM, int r, int c, unsigned short v) {
  *(unsigned short*)((char*)sM + r * 256 + ((c * 2) ^ ((r & 7) << 4))) = v;
}
// pair region: 64-row tiles, row stride 128B, same XOR swizzle
__device__ __forceinline__ bf16x8 fragP(const unsigned short* sP, int row, int kb, int lane) {
  int r = row + (lane & 15);
  int cb = (kb + ((lane >> 4) << 3)) * 2;
  return *(const bf16x8*)((const char*)sP + r * 128 + (cb ^ ((r & 7) << 4)));
}
__device__ __forceinline__ void putP16(unsigned short* sP, int r, int c, unsigned short v) {
  *(unsigned short*)((char*)sP + r * 128 + ((c * 2) ^ ((r & 7) << 4))) = v;
}
// Adj counts: u8 [128][128], row stride 128B, byte col ^= (row&7)<<3
__device__ __forceinline__ bf16x8 adjFrag(const unsigned char* sCc, const float* sInv,
                                          int mBase, int kb, int lane) {
  int m = mBase + (lane & 15);
  int c = (kb + ((lane >> 4) << 3)) ^ ((m & 7) << 3);
  const unsigned int* p = (const unsigned int*)(sCc + m * 128 + c);
  unsigned int w0 = p[0], w1 = p[1];
  float inv = sInv[m];
  unsigned short hh[8];
#pragma unroll
  for (int i = 0; i < 4; i++) {
    hh[i]     = f2bf((float)((w0 >> (8 * i)) & 0xffu) * inv);
    hh[4 + i] = f2bf((float)((w1 >> (8 * i)) & 0xffu) * inv);
  }
  return *(bf16x8*)hh;
}

// ---------------- prep: bf16-transpose weights + fold BN into mul/add ----------------
__global__ void prep_kernel(const float* __restrict__ Wc0s, const float* __restrict__ Wc0n,
                            const float* __restrict__ Wc1s, const float* __restrict__ Wc1n,
                            const float* __restrict__ Wa,
                            const float* __restrict__ bc0, const float* __restrict__ g0,
                            const float* __restrict__ b0, const float* __restrict__ m0,
                            const float* __restrict__ v0,
                            const float* __restrict__ bc1, const float* __restrict__ g1,
                            const float* __restrict__ b1, const float* __restrict__ m1,
                            const float* __restrict__ v1,
                            unsigned short* __restrict__ wbf, float* __restrict__ cst) {
  int t = blockIdx.x * blockDim.x + threadIdx.x;
  if (t < 8192) {                       // 64x128 -> [d][f]
    int d = t >> 6, f = t & 63;
    wbf[t]        = f2bf(Wc0s[f * 128 + d]);
    wbf[8192 + t] = f2bf(Wc0n[f * 128 + d]);
  } else if (t < 24576) {               // 128x128 -> [d][k]
    int i = t - 8192;
    int d = i >> 7, k = i & 127;
    wbf[16384 + i] = f2bf(Wc1s[k * 128 + d]);
    wbf[32768 + i] = f2bf(Wc1n[k * 128 + d]);
    wbf[49152 + i] = f2bf(Wa[k * 128 + d]);
  } else if (t < 24704) {
    int d = t - 24576;
    float s0 = g0[d] * rsqrtf(v0[d] + 1e-5f);
    cst[d]       = s0;
    cst[128 + d] = (bc0[d] - m0[d]) * s0 + b0[d];
    float s1 = g1[d] * rsqrtf(v1[d] + 1e-5f);
    cst[256 + d] = s1;
    cst[384 + d] = (bc1[d] - m1[d]) * s1 + b1[d];
  }
}

// ---------------- fused per-graph kernel: 1 block = 1 graph, ~51KB LDS ----------------
__global__ __launch_bounds__(512, 4)
void gnn_fused(const float* __restrict__ x, const float* __restrict__ mwt,
               const int* __restrict__ ei,
               const unsigned short* __restrict__ wbf, const float* __restrict__ cst,
               const float* __restrict__ ba,
               const float* __restrict__ Wr0, const float* __restrict__ br0,
               const float* __restrict__ Wr1, const float* __restrict__ br1,
               const float* __restrict__ Wout, const float* __restrict__ bout,
               float* __restrict__ out) {
  __shared__ unsigned short sM[128 * 128];   // 32KB: x / V^T / h / p / p^T (swizzled)
  __shared__ unsigned char  sC[128 * 128];   // 16KB: Adj u8 counts -> pair+pairT bf16
  __shared__ float sInv[128];
  __shared__ float sPool[128];
  __shared__ float sV1[128];
  __shared__ float sOut;

  const int g = blockIdx.x;
  const int t = threadIdx.x;
  const int lane = t & 63;
  const int w = t >> 6;              // wave 0..7
  const int col = lane & 15;
  const int r0 = (lane >> 4) << 2;
  const f32x4 zero = {0.f, 0.f, 0.f, 0.f};

  // ---- P0a: zero counts + pool
  {
    unsigned int* c32 = (unsigned int*)sC;
    for (int i = t; i < 4096; i += 512) c32[i] = 0u;
    if (t < 128) sPool[t] = 0.f;
    if (t == 0) sOut = 0.f;
  }
  __syncthreads();

  // ---- P0b: edge histogram (swizzled u8 grid) + x -> sM (bf16, swizzled)
  {
    int e = g * 512 + t;
    int ls_ = ei[e] & 127;
    int ld_ = ei[N_EDGES_C + e] & 127;
    int cb = ls_ ^ ((ld_ & 7) << 3);
    int idx = ld_ * 128 + cb;
    atomicAdd((unsigned int*)(sC + (idx & ~3)), 1u << ((idx & 3) * 8));
  }
  {
    const float4* xg = (const float4*)(x + (size_t)g * 8192);
#pragma unroll
    for (int i = 0; i < 4; i++) {
      int vi = t + i * 512;
      float4 v = xg[vi];
      int node = vi >> 4;
      int f = (vi & 15) * 4;
      us4 q = {f2bf(v.x), f2bf(v.y), f2bf(v.z), f2bf(v.w)};
      *(us4*)((char*)sM + node * 256 + ((f * 2) ^ ((node & 7) << 4))) = q;
    }
  }
  __syncthreads();

  // ---- P0c: inv_deg from row sums (swizzle permutes within row -> sum invariant)
  if (t < 128) {
    const unsigned int* row = (const unsigned int*)(sC + t * 128);
    int ssum = 0;
#pragma unroll
    for (int i = 0; i < 32; i++) {
      unsigned int v = row[i];
      ssum += (int)(v & 0xff) + (int)((v >> 8) & 0xff) + (int)((v >> 16) & 0xff) + (int)(v >> 24);
    }
    sInv[t] = 1.f / (float)(ssum > 1 ? ssum : 1);
  }

  f32x4 acc[8];

  // ================= Layer 0 (K_in = 64) =================
  {
    bf16x8 xA[2];
#pragma unroll
    for (int kb = 0; kb < 2; kb++) xA[kb] = fragM(sM, w * 16, kb * 32, lane);
#pragma unroll
    for (int n = 0; n < 8; n++) acc[n] = zero;
    for (int kb = 0; kb < 2; kb++)
#pragma unroll
      for (int n = 0; n < 8; n++)
        acc[n] = MFMA16(xA[kb], fragG(wbf + 8192, 64, n * 16, kb * 32, lane), acc[n]);  // V0 = x@W0n
    __syncthreads();  // all preloads (and sInv) done before V^T overwrites x
#pragma unroll
    for (int n = 0; n < 8; n++) {  // write V0^T[d][node]
      us4 q = {f2bf(acc[n][0]), f2bf(acc[n][1]), f2bf(acc[n][2]), f2bf(acc[n][3])};
      int d = n * 16 + col;
      *(us4*)((char*)sM + d * 256 + (((w * 16 + r0) * 2) ^ ((d & 7) << 4))) = q;
    }
    __syncthreads();
#pragma unroll
    for (int n = 0; n < 8; n++) acc[n] = zero;
    for (int kb = 0; kb < 2; kb++)
#pragma unroll
      for (int n = 0; n < 8; n++)
        acc[n] = MFMA16(xA[kb], fragG(wbf, 64, n * 16, kb * 32, lane), acc[n]);         // + x@W0s
    for (int kb = 0; kb < 4; kb++) {
      bf16x8 aF = adjFrag(sC, sInv, w * 16, kb * 32, lane);
#pragma unroll
      for (int n = 0; n < 8; n++)
        acc[n] = MFMA16(aF, fragM(sM, n * 16, kb * 32, lane), acc[n]);                  // + Adjn@V0
    }
    __syncthreads();  // all V0^T reads done before h1 writes
#pragma unroll
    for (int n = 0; n < 8; n++) {  // BN0 + leaky -> h1[node][d]
      int d = n * 16 + col;
      float mul = cst[d], add = cst[128 + d];
#pragma unroll
      for (int r = 0; r < 4; r++) {
        float v = acc[n][r] * mul + add;
        v = v > 0.f ? v : 0.01f * v;
        putU16(sM, w * 16 + r0 + r, d, f2bf(v));
      }
    }
    // no barrier: next phase preloads only this wave's own rows
  }

  // ================= Layer 1 (K = 128) =================
  {
    bf16x8 hA[4];
#pragma unroll
    for (int kb = 0; kb < 4; kb++) hA[kb] = fragM(sM, w * 16, kb * 32, lane);
#pragma unroll
    for (int n = 0; n < 8; n++) acc[n] = zero;
    for (int kb = 0; kb < 4; kb++)
#pragma unroll
      for (int n = 0; n < 8; n++)
        acc[n] = MFMA16(hA[kb], fragG(wbf + 32768, 128, n * 16, kb * 32, lane), acc[n]); // V1 = h1@W1n
    __syncthreads();
#pragma unroll
    for (int n = 0; n < 8; n++) {
      us4 q = {f2bf(acc[n][0]), f2bf(acc[n][1]), f2bf(acc[n][2]), f2bf(acc[n][3])};
      int d = n * 16 + col;
      *(us4*)((char*)sM + d * 256 + (((w * 16 + r0) * 2) ^ ((d & 7) << 4))) = q;
    }
    __syncthreads();
#pragma unroll
    for (int n = 0; n < 8; n++) acc[n] = zero;
    for (int kb = 0; kb < 4; kb++)
#pragma unroll
      for (int n = 0; n < 8; n++)
        acc[n] = MFMA16(hA[kb], fragG(wbf + 16384, 128, n * 16, kb * 32, lane), acc[n]); // + h1@W1s
    for (int kb = 0; kb < 4; kb++) {
      bf16x8 aF = adjFrag(sC, sInv, w * 16, kb * 32, lane);
#pragma unroll
      for (int n = 0; n < 8; n++)
        acc[n] = MFMA16(aF, fragM(sM, n * 16, kb * 32, lane), acc[n]);                   // + Adjn@V1
    }
    float mwr[4];
#pragma unroll
    for (int r = 0; r < 4; r++) mwr[r] = mwt[(size_t)g * 128 + w * 16 + r0 + r];
    __syncthreads();  // all V1^T reads done before h2 writes
#pragma unroll
    for (int n = 0; n < 8; n++) {  // BN1 + leaky + *mw -> h2; fold residual into pool
      int d = n * 16 + col;
      float mul = cst[256 + d], add = cst[384 + d];
      float csum = 0.f;
#pragma unroll
      for (int r = 0; r < 4; r++) {
        float v = acc[n][r] * mul + add;
        v = v > 0.f ? v : 0.01f * v;
        v *= mwr[r];
        putU16(sM, w * 16 + r0 + r, d, f2bf(v));
        csum += v;
      }
      csum += __shfl_xor(csum, 16);
      csum += __shfl_xor(csum, 32);
      if (lane < 16) atomicAdd(&sPool[d], csum);
    }
    // no barrier: P3 preloads only own rows
  }

  // ---- P3: p = leaky(h2@Wa + ba) -> overwrite own rows of sM
  {
    bf16x8 hA[4];
#pragma unroll
    for (int kb = 0; kb < 4; kb++) hA[kb] = fragM(sM, w * 16, kb * 32, lane);
#pragma unroll
    for (int n = 0; n < 8; n++) acc[n] = zero;
    for (int kb = 0; kb < 4; kb++)
#pragma unroll
      for (int n = 0; n < 8; n++)
        acc[n] = MFMA16(hA[kb], fragG(wbf + 49152, 128, n * 16, kb * 32, lane), acc[n]);
#pragma unroll
    for (int n = 0; n < 8; n++) {
      int d = n * 16 + col;
      float bav = ba[d];
#pragma unroll
      for (int r = 0; r < 4; r++) {
        float v = acc[n][r] + bav;
        v = v > 0.f ? v : 0.01f * v;
        putU16(sM, w * 16 + r0 + r, d, f2bf(v));
      }
    }
  }
  __syncthreads();  // p complete for all rows

  // ---- P6: pair = sigmoid(pA@pB^T) -> sC (counts dead): pair[0..63], pairT at +4096
  {
    unsigned short* sP = (unsigned short*)sC;
    f32x4 acc2[2] = {zero, zero};
    for (int kb = 0; kb < 128; kb += 32) {
#pragma unroll
      for (int i = 0; i < 2; i++) {
        int T = w * 2 + i;
        bf16x8 a = fragM(sM, (T >> 2) * 16, kb, lane);
        bf16x8 b = fragM(sM, 64 + (T & 3) * 16, kb, lane);
        acc2[i] = MFMA16(a, b, acc2[i]);
      }
    }
#pragma unroll
    for (int i = 0; i < 2; i++) {
      int T = w * 2 + i, mb = (T >> 2) * 16, nb = (T & 3) * 16;
#pragma unroll
      for (int r = 0; r < 4; r++) {
        float v = 1.f / (1.f + __expf(-acc2[i][r]));
        unsigned short u = f2bf(v);
        putP16(sP, mb + r0 + r, nb + col, u);
        putP16(sP + 4096, nb + col, mb + r0 + r, u);
      }
    }
  }

  // ---- Ptr: in-place transpose of p (4x4 u16 blocks, 2 per thread)
  {
    us4 rd[2][4];
#pragma unroll
    for (int b = 0; b < 2; b++) {
      int id = t + b * 512, R = id >> 5, C = id & 31;
#pragma unroll
      for (int j = 0; j < 4; j++) {
        int r = 4 * R + j;
        rd[b][j] = *(const us4*)((const char*)sM + r * 256 + ((C * 8) ^ ((r & 7) << 4)));
      }
    }
    __syncthreads();  // all p reads (P6 MFMAs + block reads) done
#pragma unroll
    for (int b = 0; b < 2; b++) {
      int id = t + b * 512, R = id >> 5, C = id & 31;
#pragma unroll
      for (int cc = 0; cc < 4; cc++) {
        us4 o = {rd[b][0][cc], rd[b][1][cc], rd[b][2][cc], rd[b][3][cc]};
        int r = 4 * C + cc;
        *(us4*)((char*)sM + r * 256 + ((R * 8) ^ ((r & 7) << 4))) = o;
      }
    }
  }
  __syncthreads();

  // ---- P7: newA_delta = pair@pB (w0-3) / newB_delta = pairT@pA (w4-7) -> pool only
  {
    const unsigned short* sP = (const unsigned short*)sC;
    const int isB = w >> 2;
    const int mr = (w & 3) * 16;
#pragma unroll
    for (int n = 0; n < 8; n++) acc[n] = zero;
    for (int kb = 0; kb < 64; kb += 32) {
      bf16x8 a = fragP(sP + (isB ? 4096 : 0), mr, kb, lane);
      int koff = isB ? kb : 64 + kb;
#pragma unroll
      for (int n = 0; n < 8; n++) {
        bf16x8 bfr = fragM(sM, n * 16, koff, lane);  // p^T[d][node]
        acc[n] = MFMA16(a, bfr, acc[n]);
      }
    }
#pragma unroll
    for (int n = 0; n < 8; n++) {
      int d = n * 16 + col;
      float csum = acc[n][0] + acc[n][1] + acc[n][2] + acc[n][3];
      csum += __shfl_xor(csum, 16);
      csum += __shfl_xor(csum, 32);
      if (lane < 16) atomicAdd(&sPool[d], csum);
    }
  }
  __syncthreads();

  // ---- P8: readout
  if (t < 128) sPool[t] *= (1.f / 128.f);
  __syncthreads();
  {
    int d = t >> 2, q = t & 3;
    float s = 0.f;
    for (int j = q * 32; j < q * 32 + 32; j++) s += sPool[j] * Wr0[j * 128 + d];
    s += __shfl_xor(s, 1);
    s += __shfl_xor(s, 2);
    if (q == 0) { s += br0[d]; sV1[d] = s > 0.f ? s : 0.01f * s; }
  }
  __syncthreads();
  {
    int d = t >> 2, q = t & 3;
    float s = 0.f;
    for (int j = q * 32; j < q * 32 + 32; j++) s += sV1[j] * Wr1[j * 128 + d];
    s += __shfl_xor(s, 1);
    s += __shfl_xor(s, 2);
    if (q == 0) { s += br1[d]; sPool[d] = s > 0.f ? s : 0.01f * s; }
  }
  __syncthreads();
  if (t < 128) atomicAdd(&sOut, sPool[t] * Wout[t]);
  __syncthreads();
  if (t == 0) out[g] = sOut + bout[0];
}

extern "C" void kernel_launch(void* const* d_in, const int* in_sizes, int n_in,
                              void* d_out, int out_size, void* d_ws, size_t ws_size,
                              hipStream_t stream) {
  const float* x     = (const float*)d_in[0];
  const float* mwt   = (const float*)d_in[1];
  const float* Wc0s  = (const float*)d_in[2];
  const float* Wc0n  = (const float*)d_in[3];
  const float* bc0   = (const float*)d_in[4];
  const float* g0    = (const float*)d_in[5];
  const float* b0    = (const float*)d_in[6];
  const float* m0    = (const float*)d_in[7];
  const float* v0    = (const float*)d_in[8];
  const float* Wc1s  = (const float*)d_in[9];
  const float* Wc1n  = (const float*)d_in[10];
  const float* bc1   = (const float*)d_in[11];
  const float* g1    = (const float*)d_in[12];
  const float* b1    = (const float*)d_in[13];
  const float* m1    = (const float*)d_in[14];
  const float* v1    = (const float*)d_in[15];
  const float* Wa    = (const float*)d_in[16];
  const float* ba    = (const float*)d_in[17];
  const float* Wr0   = (const float*)d_in[18];
  const float* br0   = (const float*)d_in[19];
  const float* Wr1   = (const float*)d_in[20];
  const float* br1   = (const float*)d_in[21];
  const float* Wout  = (const float*)d_in[22];
  const float* bout  = (const float*)d_in[23];
  const int*   ei    = (const int*)d_in[24];

  unsigned short* wbf = (unsigned short*)d_ws;
  float* cst = (float*)((char*)d_ws + 131072);

  prep_kernel<<<dim3(97), dim3(256), 0, stream>>>(Wc0s, Wc0n, Wc1s, Wc1n, Wa,
                                                  bc0, g0, b0, m0, v0,
                                                  bc1, g1, b1, m1, v1, wbf, cst);
  gnn_fused<<<dim3(2048), dim3(512), 0, stream>>>(x, mwt, ei, wbf, cst, ba,
                                                  Wr0, br0, Wr1, br1, Wout, bout,
                                                  (float*)d_out);
}